// Round 10
// baseline (90133.258 us; speedup 1.0000x reference)
//
#include <hip/hip_runtime.h>

#define SS 16384
#define DD 1024
#define HH 1024
#define G4H 4096

typedef unsigned long long u64;
typedef unsigned int u32;
typedef unsigned short ushort_t;

typedef __attribute__((ext_vector_type(8))) short bf16x8;
typedef __attribute__((ext_vector_type(4))) float f32x4;
typedef _Float16 h2 __attribute__((ext_vector_type(2)));

__device__ __forceinline__ float sigm(float x){ return 1.0f/(1.0f+__expf(-x)); }
__device__ __forceinline__ float tanh_fast(float x){ return 1.0f - 2.0f/(__expf(2.0f*x)+1.0f); }

__device__ __forceinline__ ushort_t f2bf(float f){
    u32 u = __float_as_uint(f);
    u32 r = (u + 0x7FFFu + ((u>>16)&1u)) >> 16;
    return (ushort_t)r;
}

#if __has_builtin(__builtin_amdgcn_fdot2)
__device__ __forceinline__ float fdot2f(h2 a, h2 b, float c){
    return __builtin_amdgcn_fdot2(a, b, c, false);
}
#else
__device__ __forceinline__ float fdot2f(h2 a, h2 b, float c){
    return c + (float)a.x*(float)b.x + (float)a.y*(float)b.y;
}
#endif

// ---------------- prep: fp32 -> bf16 conversions + bias ----------------
__global__ __launch_bounds__(256) void prep_kernel(
    const float* __restrict__ x, const float* __restrict__ wih,
    const float* __restrict__ bih, const float* __restrict__ bhh,
    ushort_t* __restrict__ xb, ushort_t* __restrict__ wb, float* __restrict__ bias)
{
    long long i = (long long)blockIdx.x*256 + threadIdx.x;
    const long long NX = (long long)SS*DD;      // 16777216
    const long long NW = (long long)G4H*DD;     // 4194304
    if (i < NX) { xb[i] = f2bf(x[i]); }
    else if (i < NX+NW) { long long j=i-NX; wb[j]=f2bf(wih[j]); }
    else { int j=(int)(i-NX-NW); if (j < G4H) bias[j]=bih[j]+bhh[j]; }
}

// ---------------- GEMM: xg = x @ W_ih^T + bias, fp16 out ----------------
#define LDA 40  // padded LDS row stride (bf16 elems)

__global__ __launch_bounds__(256) void gemm_kernel(
    const ushort_t* __restrict__ A, const ushort_t* __restrict__ B,
    const float* __restrict__ bias, _Float16* __restrict__ Cg)
{
    __shared__ ushort_t At[128*LDA];
    __shared__ ushort_t Bt[128*LDA];
    const int tid  = threadIdx.x;
    const int lane = tid & 63;
    const int wv   = tid >> 6;
    const int wm   = wv >> 1, wn = wv & 1;
    const int m0   = blockIdx.y * 128;
    const int n0   = blockIdx.x * 128;
    const int quad = lane >> 4;
    const int l16  = lane & 15;

    f32x4 acc[4][4];
    #pragma unroll
    for (int a=0;a<4;a++)
      #pragma unroll
      for (int b=0;b<4;b++) acc[a][b] = (f32x4){0.f,0.f,0.f,0.f};

    for (int kb = 0; kb < DD; kb += 32) {
        #pragma unroll
        for (int s=0;s<2;s++){
            int ch  = tid*2+s;            // 0..511
            int row = ch >> 2;
            int ko  = (ch & 3) * 8;
            uint4 va = *(const uint4*)(A + (long long)(m0+row)*DD + kb + ko);
            *(uint4*)(At + row*LDA + ko) = va;
            uint4 vb = *(const uint4*)(B + (long long)(n0+row)*DD + kb + ko);
            *(uint4*)(Bt + row*LDA + ko) = vb;
        }
        __syncthreads();
        bf16x8 af[4], bfr[4];
        #pragma unroll
        for (int mi=0;mi<4;mi++){
            int r = wm*64 + mi*16 + l16;
            af[mi] = *(const bf16x8*)(At + r*LDA + quad*8);
        }
        #pragma unroll
        for (int ni=0;ni<4;ni++){
            int r = wn*64 + ni*16 + l16;
            bfr[ni] = *(const bf16x8*)(Bt + r*LDA + quad*8);
        }
        #pragma unroll
        for (int mi=0;mi<4;mi++)
          #pragma unroll
          for (int ni=0;ni<4;ni++)
            acc[mi][ni] = __builtin_amdgcn_mfma_f32_16x16x32_bf16(af[mi], bfr[ni], acc[mi][ni], 0,0,0);
        __syncthreads();
    }
    #pragma unroll
    for (int mi=0;mi<4;mi++){
      #pragma unroll
      for (int ni=0;ni<4;ni++){
        int col = n0 + wn*64 + ni*16 + l16;
        float bv = bias[col];
        #pragma unroll
        for (int r=0;r<4;r++){
            int rowg = m0 + wm*64 + mi*16 + quad*4 + r;
            Cg[(long long)rowg*G4H + col] = (_Float16)(acc[mi][ni][r] + bv);
        }
      }
    }
}

// ---------------- persistent LSTM scan ----------------
// Round-4 per-wave structure, geometry scaled along the ONLY axis that ever
// produced a big win (r3->r4: 256->64 blocks = 1.7x): now 16 blocks x 16
// waves (1024 thr), block owns 64 units, each wave 4 (identical per-wave
// work/VGPR as r4). Wave 0 polls + stages with r4's exact 4-load + sleep(1)
// throttle code. Deltas vs r4:
//  - line-requests/retry-round: 64x16 -> 16x16 = 256 (4x less LLC pressure)
//  - producer jitter population: max-of-64 -> max-of-16 per step
//  - each block's 16 u64 output = exactly one aligned 128B line, written by
//    ONE CU (r4: 4 CUs shared each line) -> no cross-CU store serialization
//  - barrier widens 4 -> 16 waves (+~100cy, accepted)
// Lane map (unchanged): lane = 16*rr + cc; unit rr (of the wave's 4), all 4
// gates, h-cols [64cc, 64cc+63]; packed-f16 v_dot2; 4-level shfl_xor reduce
// within 16-lane groups; chunk rotation by cc on W-load and h-LDS-read.
__device__ __forceinline__ bool has_sent(u64 v){
    u32 lo = (u32)v, hi = (u32)(v>>32);
    return ((lo & 0xFFFFu)==0xFFFFu) | ((lo>>16)==0xFFFFu) |
           ((hi & 0xFFFFu)==0xFFFFu) | ((hi>>16)==0xFFFFu);
}

__global__ __launch_bounds__(1024, 1) void scan_kernel(
    const float* __restrict__ whh, const _Float16* __restrict__ xg,
    u64* __restrict__ packed)
{
    __shared__ u64 hbuf[2][256];
    const int tid  = threadIdx.x;
    const int lane = tid & 63;
    const int wvid = tid >> 6;        // 0..15
    const int rr   = lane >> 4;       // unit-in-wave 0..3
    const int cc   = lane & 15;       // 64-col chunk 0..15
    const int hu   = blockIdx.x*64 + wvid*4 + rr;

    // W_hh slice: gate j row (j*HH + hu), cols 64*cc + [0..63], as packed
    // f16 pairs, chunk-rotated by cc (8 f16 per 16B chunk).
    h2 W[4][32];
    #pragma unroll
    for (int j=0;j<4;j++){
        const float* rp = whh + (long long)(j*HH + hu)*HH + 64*cc;
        #pragma unroll
        for (int m=0;m<8;m++){
            int g = (m + cc) & 7;
            float4 v0 = *(const float4*)(rp + 8*g);
            float4 v1 = *(const float4*)(rp + 8*g + 4);
            h2 a, b, c2, d;
            a.x=(_Float16)v0.x; a.y=(_Float16)v0.y;
            b.x=(_Float16)v0.z; b.y=(_Float16)v0.w;
            c2.x=(_Float16)v1.x; c2.y=(_Float16)v1.y;
            d.x=(_Float16)v1.z; d.y=(_Float16)v1.w;
            W[j][4*m+0]=a; W[j][4*m+1]=b; W[j][4*m+2]=c2; W[j][4*m+3]=d;
        }
    }

    float c_st = 0.0f;
    float xgc[4];
    #pragma unroll
    for (int j=0;j<4;j++) xgc[j] = (float)xg[(long long)j*HH + hu];

    for (int t=0; t<SS; ++t){
        const int par = t & 1;
        // prefetch next step's xg (overlaps the poll)
        float xgn[4] = {0.f,0.f,0.f,0.f};
        if (t+1 < SS){
            #pragma unroll
            for (int j=0;j<4;j++)
                xgn[j] = (float)xg[(long long)(t+1)*G4H + j*HH + hu];
        }

        if (wvid == 0){
            if (t == 0){
                hbuf[0][lane]=0; hbuf[0][lane+64]=0;
                hbuf[0][lane+128]=0; hbuf[0][lane+192]=0;
            } else {
                const u64* src = packed + (long long)(t-1)*256 + lane;
                u64 v0=0,v1=0,v2=0,v3=0;
                int spin = 0;
                for (;;){
                    v0 = __hip_atomic_load(src      , __ATOMIC_RELAXED, __HIP_MEMORY_SCOPE_AGENT);
                    v1 = __hip_atomic_load(src +  64, __ATOMIC_RELAXED, __HIP_MEMORY_SCOPE_AGENT);
                    v2 = __hip_atomic_load(src + 128, __ATOMIC_RELAXED, __HIP_MEMORY_SCOPE_AGENT);
                    v3 = __hip_atomic_load(src + 192, __ATOMIC_RELAXED, __HIP_MEMORY_SCOPE_AGENT);
                    if (!(has_sent(v0)|has_sent(v1)|has_sent(v2)|has_sent(v3))) break;
                    if (++spin > (1<<19)) break;   // deadlock insurance
                    if (spin > 1024) __builtin_amdgcn_s_sleep(8);
                    else             __builtin_amdgcn_s_sleep(1);
                }
                hbuf[par][lane]     = v0;
                hbuf[par][lane+64]  = v1;
                hbuf[par][lane+128] = v2;
                hbuf[par][lane+192] = v3;
            }
        }
        __syncthreads();

        // read this lane's 128B h slice, chunk-rotated (matches W rotation)
        union { uint4 v4[8]; h2 hh[32]; } H;
        {
            const char* hb = (const char*)(hbuf[par] + 16*cc);
            #pragma unroll
            for (int m=0;m<8;m++){
                H.v4[m] = *(const uint4*)(hb + 16*((m+cc)&7));
            }
        }

        float s0=0.f, s1=0.f, s2=0.f, s3=0.f;
        #pragma unroll
        for (int m=0;m<32;m++){
            s0 = fdot2f(W[0][m], H.hh[m], s0);
            s1 = fdot2f(W[1][m], H.hh[m], s1);
            s2 = fdot2f(W[2][m], H.hh[m], s2);
            s3 = fdot2f(W[3][m], H.hh[m], s3);
        }
        // reduce over the 16 cc-lanes of this rr-group
        #pragma unroll
        for (int off=8; off>=1; off>>=1){
            s0 += __shfl_xor(s0, off, 64);
            s1 += __shfl_xor(s1, off, 64);
            s2 += __shfl_xor(s2, off, 64);
            s3 += __shfl_xor(s3, off, 64);
        }
        // every lane in group rr now holds unit hu's complete gate sums
        float zi = s0 + xgc[0];
        float zf = s1 + xgc[1];
        float zg = s2 + xgc[2];
        float zo = s3 + xgc[3];
        c_st = sigm(zf)*c_st + sigm(zi)*tanh_fast(zg);
        float hval = sigm(zo)*tanh_fast(c_st);

        union { _Float16 h; ushort_t u; } hb16; hb16.h = (_Float16)hval;
        int hbits = (int)hb16.u;
        u32 b0 = (u32)__shfl(hbits,  0, 64);
        u32 b1 = (u32)__shfl(hbits, 16, 64);
        u32 b2 = (u32)__shfl(hbits, 32, 64);
        u32 b3 = (u32)__shfl(hbits, 48, 64);
        if (lane == 0){
            u64 pk = (u64)(b0 & 0xFFFFu)
                   | ((u64)(b1 & 0xFFFFu) << 16)
                   | ((u64)(b2 & 0xFFFFu) << 32)
                   | ((u64)(b3 & 0xFFFFu) << 48);
            __hip_atomic_store(packed + (long long)t*256 + blockIdx.x*16 + wvid, pk,
                               __ATOMIC_RELAXED, __HIP_MEMORY_SCOPE_AGENT);
        }
        xgc[0]=xgn[0]; xgc[1]=xgn[1]; xgc[2]=xgn[2]; xgc[3]=xgn[3];
    }
}

// ---------------- alpha = sigmoid(hs @ W_fc^T + b_fc) ----------------
__global__ __launch_bounds__(256) void alpha_kernel(
    const u64* __restrict__ packed, const float* __restrict__ wfc,
    const float* __restrict__ bfc, float* __restrict__ alpha)
{
    int row  = blockIdx.x*4 + (threadIdx.x>>6);
    int lane = threadIdx.x & 63;
    const u64* p = packed + (long long)row*256 + 4*lane;
    float s = 0.f;
    #pragma unroll
    for (int q=0;q<4;q++){
        union { u64 u; _Float16 h[4]; } cv; cv.u = p[q];
        float4 wvv = *(const float4*)(wfc + 16*lane + 4*q);
        s += (float)cv.h[0]*wvv.x + (float)cv.h[1]*wvv.y
           + (float)cv.h[2]*wvv.z + (float)cv.h[3]*wvv.w;
    }
    #pragma unroll
    for (int off=32; off>=1; off>>=1) s += __shfl_xor(s, off, 64);
    if (lane==0) alpha[row] = sigm(s + bfc[0]);
}

// ---------------- finalize: affine scans + loss ----------------
__global__ __launch_bounds__(256) void finalize_kernel(
    const float* __restrict__ uttr_pred, const float* __restrict__ timing_label,
    const float* __restrict__ alpha, float* __restrict__ out)
{
    const int n = SS-1;  // 16383
    const int tid = threadIdx.x;
    __shared__ float Ms[256], Cs[256], Pre[256];
    __shared__ int Fi[256];
    float* out_y = out + 1;
    float* out_a = out + 1 + n;
    float* out_u = out + 1 + 2*n;

    int i0 = tid*64;
    int i1 = i0+64; if (i1 > n) i1 = n;

    // pass 1: u, a-scan chunk composition, first mask index
    float M = 1.f, C = 0.f;
    int fi = 0x7fffffff;
    for (int i=i0; i<i1; ++i){
        float u = 1.f - uttr_pred[i+1];
        float a = alpha[i+1];
        out_u[i] = u;
        M = u*M;
        C = u*C + (1.f-u)*a;
        if (timing_label[i] > 0.8f && i < fi) fi = i;
    }
    Ms[tid]=M; Cs[tid]=C; Fi[tid]=fi;
    __syncthreads();
    if (tid==0){
        float x=0.f;
        for (int tt=0; tt<256; ++tt){ Pre[tt]=x; x = Ms[tt]*x + Cs[tt]; }
        int best=0x7fffffff;
        for (int tt=0; tt<256; ++tt) best = min(best, Fi[tt]);
        Fi[0]=best;
    }
    __syncthreads();
    // pass 2: emit a_seq, compose y-scan chunks
    float x = Pre[tid];
    float My=1.f, Cy=0.f;
    for (int i=i0;i<i1;++i){
        float u = 1.f - uttr_pred[i+1];
        float a = alpha[i+1];
        x = u*x + (1.f-u)*a;
        out_a[i] = x;
        float Af = 1.f - x;
        float Bf = x*u;
        My = Af*My;
        Cy = Af*Cy + Bf;
    }
    Ms[tid]=My; Cs[tid]=Cy;
    __syncthreads();
    if (tid==0){
        float y=0.f;
        for (int tt=0;tt<256;++tt){ Pre[tt]=y; y = Ms[tt]*y + Cs[tt]; }
    }
    __syncthreads();
    float y = Pre[tid];
    for (int i=i0;i<i1;++i){
        float ag = out_a[i];
        float u  = out_u[i];
        y = ag*u + (1.f-ag)*y;
        out_y[i] = y;
    }
    __syncthreads();
    if (tid==0){
        int best = Fi[0];
        bool exists = (best != 0x7fffffff);
        int idx = exists ? best : 0;
        float u_at = 1.f - uttr_pred[idx+1];
        float y_at = out_y[idx];
        float y_last = out_y[n-1];
        float loss;
        if (exists) loss = (u_at < 0.5f) ? 0.f : (y_at-0.8f)*(y_at-0.8f);
        else        loss = (y_last >= 0.8f) ? (y_last-0.4f)*(y_last-0.4f) : 0.f;
        out[0] = loss;
    }
}

// ---------------- launch ----------------
extern "C" void kernel_launch(void* const* d_in, const int* in_sizes, int n_in,
                              void* d_out, int out_size, void* d_ws, size_t ws_size,
                              hipStream_t stream)
{
    const float* x    = (const float*)d_in[0];
    const float* up   = (const float*)d_in[1];
    const float* tl   = (const float*)d_in[2];
    // d_in[3] = uttr_label (unused by the math)
    const float* wih  = (const float*)d_in[4];
    const float* whh  = (const float*)d_in[5];
    const float* bih  = (const float*)d_in[6];
    const float* bhh  = (const float*)d_in[7];
    const float* wfc  = (const float*)d_in[8];
    const float* bfc  = (const float*)d_in[9];
    float* out = (float*)d_out;

    char* ws = (char*)d_ws;
    ushort_t* xb   = (ushort_t*)(ws);                      // 32 MB  x bf16
    ushort_t* wb   = (ushort_t*)(ws + 33554432);           //  8 MB  W_ih bf16
    _Float16* xg   = (_Float16*)(ws + 41943040);           // 128 MB xg fp16
    u64*      pkd  = (u64*)     (ws + 176160768);          // 32 MB  packed h history
    float*    alp  = (float*)   (ws + 209715200);          // 64 KB  alpha
    float*    bias = (float*)   (ws + 209780736);          // 16 KB  bias

    (void)hipMemsetAsync(pkd, 0xFF, (size_t)SS*HH*2, stream);   // sentinel init
    prep_kernel<<<81936, 256, 0, stream>>>(x, wih, bih, bhh, xb, wb, bias);
    gemm_kernel<<<dim3(G4H/128, SS/128), 256, 0, stream>>>(xb, wb, bias, xg);
    scan_kernel<<<16, 1024, 0, stream>>>(whh, xg, pkd);
    alpha_kernel<<<SS/4, 256, 0, stream>>>(pkd, wfc, bfc, alp);
    finalize_kernel<<<1, 256, 0, stream>>>(up, tl, alp, out);
}

// Round 11
// 46592.508 us; speedup vs baseline: 1.9345x; 1.9345x over previous
//
#include <hip/hip_runtime.h>

#define SS 16384
#define DD 1024
#define HH 1024
#define G4H 4096

typedef unsigned long long u64;
typedef unsigned int u32;
typedef unsigned short ushort_t;

typedef __attribute__((ext_vector_type(8))) short bf16x8;
typedef __attribute__((ext_vector_type(4))) float f32x4;
typedef _Float16 h2 __attribute__((ext_vector_type(2)));

__device__ __forceinline__ float sigm(float x){ return 1.0f/(1.0f+__expf(-x)); }
__device__ __forceinline__ float tanh_fast(float x){ return 1.0f - 2.0f/(__expf(2.0f*x)+1.0f); }

__device__ __forceinline__ ushort_t f2bf(float f){
    u32 u = __float_as_uint(f);
    u32 r = (u + 0x7FFFu + ((u>>16)&1u)) >> 16;
    return (ushort_t)r;
}

#if __has_builtin(__builtin_amdgcn_fdot2)
__device__ __forceinline__ float fdot2f(h2 a, h2 b, float c){
    return __builtin_amdgcn_fdot2(a, b, c, false);
}
#else
__device__ __forceinline__ float fdot2f(h2 a, h2 b, float c){
    return c + (float)a.x*(float)b.x + (float)a.y*(float)b.y;
}
#endif

// ---------------- prep: fp32 -> bf16 conversions + bias ----------------
__global__ __launch_bounds__(256) void prep_kernel(
    const float* __restrict__ x, const float* __restrict__ wih,
    const float* __restrict__ bih, const float* __restrict__ bhh,
    ushort_t* __restrict__ xb, ushort_t* __restrict__ wb, float* __restrict__ bias)
{
    long long i = (long long)blockIdx.x*256 + threadIdx.x;
    const long long NX = (long long)SS*DD;      // 16777216
    const long long NW = (long long)G4H*DD;     // 4194304
    if (i < NX) { xb[i] = f2bf(x[i]); }
    else if (i < NX+NW) { long long j=i-NX; wb[j]=f2bf(wih[j]); }
    else { int j=(int)(i-NX-NW); if (j < G4H) bias[j]=bih[j]+bhh[j]; }
}

// ---------------- GEMM: xg = x @ W_ih^T + bias, fp16 out ----------------
#define LDA 40  // padded LDS row stride (bf16 elems)

__global__ __launch_bounds__(256) void gemm_kernel(
    const ushort_t* __restrict__ A, const ushort_t* __restrict__ B,
    const float* __restrict__ bias, _Float16* __restrict__ Cg)
{
    __shared__ ushort_t At[128*LDA];
    __shared__ ushort_t Bt[128*LDA];
    const int tid  = threadIdx.x;
    const int lane = tid & 63;
    const int wv   = tid >> 6;
    const int wm   = wv >> 1, wn = wv & 1;
    const int m0   = blockIdx.y * 128;
    const int n0   = blockIdx.x * 128;
    const int quad = lane >> 4;
    const int l16  = lane & 15;

    f32x4 acc[4][4];
    #pragma unroll
    for (int a=0;a<4;a++)
      #pragma unroll
      for (int b=0;b<4;b++) acc[a][b] = (f32x4){0.f,0.f,0.f,0.f};

    for (int kb = 0; kb < DD; kb += 32) {
        #pragma unroll
        for (int s=0;s<2;s++){
            int ch  = tid*2+s;            // 0..511
            int row = ch >> 2;
            int ko  = (ch & 3) * 8;
            uint4 va = *(const uint4*)(A + (long long)(m0+row)*DD + kb + ko);
            *(uint4*)(At + row*LDA + ko) = va;
            uint4 vb = *(const uint4*)(B + (long long)(n0+row)*DD + kb + ko);
            *(uint4*)(Bt + row*LDA + ko) = vb;
        }
        __syncthreads();
        bf16x8 af[4], bfr[4];
        #pragma unroll
        for (int mi=0;mi<4;mi++){
            int r = wm*64 + mi*16 + l16;
            af[mi] = *(const bf16x8*)(At + r*LDA + quad*8);
        }
        #pragma unroll
        for (int ni=0;ni<4;ni++){
            int r = wn*64 + ni*16 + l16;
            bfr[ni] = *(const bf16x8*)(Bt + r*LDA + quad*8);
        }
        #pragma unroll
        for (int mi=0;mi<4;mi++)
          #pragma unroll
          for (int ni=0;ni<4;ni++)
            acc[mi][ni] = __builtin_amdgcn_mfma_f32_16x16x32_bf16(af[mi], bfr[ni], acc[mi][ni], 0,0,0);
        __syncthreads();
    }
    #pragma unroll
    for (int mi=0;mi<4;mi++){
      #pragma unroll
      for (int ni=0;ni<4;ni++){
        int col = n0 + wn*64 + ni*16 + l16;
        float bv = bias[col];
        #pragma unroll
        for (int r=0;r<4;r++){
            int rowg = m0 + wm*64 + mi*16 + quad*4 + r;
            Cg[(long long)rowg*G4H + col] = (_Float16)(acc[mi][ni][r] + bv);
        }
      }
    }
}

// ---------------- persistent LSTM scan ----------------
// Population-axis experiment, UNCONFOUNDED this time:
// 32 blocks x 8 waves (512 thr; r10's 1024-thr variant silently capped
// VGPR at 64 -> W[4][32] spilled to scratch -> 3.3x regression; at 512 thr
// r5 measured 116 VGPR, zero spill). Per-wave structure and poll
// discipline are byte-for-byte round-4 (the 27.3 ms optimum):
//  - wave 0 ONLY polls + stages (r5's parallel-wave poll: 46.5 ms)
//  - 4 x u64 agent loads at stride 512B (contiguous wave bursts)
//  - s_sleep(1) throttle from retry 1 (r5 removed: 1.7x; r6 A/B: +2.1ms;
//    r8 dense+sc0sc1: +2.6ms)
// Geometry deltas vs r4: pollers 64->32 waves; jitter max-of-64 ->
// max-of-32; each 128B h-line written by 2 blocks (vs 4); barrier 4->8
// waves. Block owns 32 units, wave owns 4.
// Lane map: lane = 16*rr + cc; unit rr, all 4 gates, h-cols [64cc,64cc+63];
// packed-f16 v_dot2; 4-level shfl_xor reduce in 16-lane groups; chunk
// rotation by cc on W-load and h-LDS-read.
__device__ __forceinline__ bool has_sent(u64 v){
    u32 lo = (u32)v, hi = (u32)(v>>32);
    return ((lo & 0xFFFFu)==0xFFFFu) | ((lo>>16)==0xFFFFu) |
           ((hi & 0xFFFFu)==0xFFFFu) | ((hi>>16)==0xFFFFu);
}

__global__ __launch_bounds__(512, 1) void scan_kernel(
    const float* __restrict__ whh, const _Float16* __restrict__ xg,
    u64* __restrict__ packed)
{
    __shared__ u64 hbuf[2][256];
    const int tid  = threadIdx.x;
    const int lane = tid & 63;
    const int wvid = tid >> 6;        // 0..7
    const int rr   = lane >> 4;       // unit-in-wave 0..3
    const int cc   = lane & 15;       // 64-col chunk 0..15
    const int hu   = blockIdx.x*32 + wvid*4 + rr;

    // W_hh slice: gate j row (j*HH + hu), cols 64*cc + [0..63], as packed
    // f16 pairs, chunk-rotated by cc (8 f16 per 16B chunk).
    h2 W[4][32];
    #pragma unroll
    for (int j=0;j<4;j++){
        const float* rp = whh + (long long)(j*HH + hu)*HH + 64*cc;
        #pragma unroll
        for (int m=0;m<8;m++){
            int g = (m + cc) & 7;
            float4 v0 = *(const float4*)(rp + 8*g);
            float4 v1 = *(const float4*)(rp + 8*g + 4);
            h2 a, b, c2, d;
            a.x=(_Float16)v0.x; a.y=(_Float16)v0.y;
            b.x=(_Float16)v0.z; b.y=(_Float16)v0.w;
            c2.x=(_Float16)v1.x; c2.y=(_Float16)v1.y;
            d.x=(_Float16)v1.z; d.y=(_Float16)v1.w;
            W[j][4*m+0]=a; W[j][4*m+1]=b; W[j][4*m+2]=c2; W[j][4*m+3]=d;
        }
    }

    float c_st = 0.0f;
    float xgc[4];
    #pragma unroll
    for (int j=0;j<4;j++) xgc[j] = (float)xg[(long long)j*HH + hu];

    for (int t=0; t<SS; ++t){
        const int par = t & 1;
        // prefetch next step's xg (overlaps the poll)
        float xgn[4] = {0.f,0.f,0.f,0.f};
        if (t+1 < SS){
            #pragma unroll
            for (int j=0;j<4;j++)
                xgn[j] = (float)xg[(long long)(t+1)*G4H + j*HH + hu];
        }

        if (wvid == 0){
            if (t == 0){
                hbuf[0][lane]=0; hbuf[0][lane+64]=0;
                hbuf[0][lane+128]=0; hbuf[0][lane+192]=0;
            } else {
                const u64* src = packed + (long long)(t-1)*256 + lane;
                u64 v0=0,v1=0,v2=0,v3=0;
                int spin = 0;
                for (;;){
                    v0 = __hip_atomic_load(src      , __ATOMIC_RELAXED, __HIP_MEMORY_SCOPE_AGENT);
                    v1 = __hip_atomic_load(src +  64, __ATOMIC_RELAXED, __HIP_MEMORY_SCOPE_AGENT);
                    v2 = __hip_atomic_load(src + 128, __ATOMIC_RELAXED, __HIP_MEMORY_SCOPE_AGENT);
                    v3 = __hip_atomic_load(src + 192, __ATOMIC_RELAXED, __HIP_MEMORY_SCOPE_AGENT);
                    if (!(has_sent(v0)|has_sent(v1)|has_sent(v2)|has_sent(v3))) break;
                    if (++spin > (1<<19)) break;   // deadlock insurance
                    if (spin > 1024) __builtin_amdgcn_s_sleep(8);
                    else             __builtin_amdgcn_s_sleep(1);
                }
                hbuf[par][lane]     = v0;
                hbuf[par][lane+64]  = v1;
                hbuf[par][lane+128] = v2;
                hbuf[par][lane+192] = v3;
            }
        }
        __syncthreads();

        // read this lane's 128B h slice, chunk-rotated (matches W rotation)
        union { uint4 v4[8]; h2 hh[32]; } H;
        {
            const char* hb = (const char*)(hbuf[par] + 16*cc);
            #pragma unroll
            for (int m=0;m<8;m++){
                H.v4[m] = *(const uint4*)(hb + 16*((m+cc)&7));
            }
        }

        float s0=0.f, s1=0.f, s2=0.f, s3=0.f;
        #pragma unroll
        for (int m=0;m<32;m++){
            s0 = fdot2f(W[0][m], H.hh[m], s0);
            s1 = fdot2f(W[1][m], H.hh[m], s1);
            s2 = fdot2f(W[2][m], H.hh[m], s2);
            s3 = fdot2f(W[3][m], H.hh[m], s3);
        }
        // reduce over the 16 cc-lanes of this rr-group
        #pragma unroll
        for (int off=8; off>=1; off>>=1){
            s0 += __shfl_xor(s0, off, 64);
            s1 += __shfl_xor(s1, off, 64);
            s2 += __shfl_xor(s2, off, 64);
            s3 += __shfl_xor(s3, off, 64);
        }
        // every lane in group rr now holds unit hu's complete gate sums
        float zi = s0 + xgc[0];
        float zf = s1 + xgc[1];
        float zg = s2 + xgc[2];
        float zo = s3 + xgc[3];
        c_st = sigm(zf)*c_st + sigm(zi)*tanh_fast(zg);
        float hval = sigm(zo)*tanh_fast(c_st);

        union { _Float16 h; ushort_t u; } hb16; hb16.h = (_Float16)hval;
        int hbits = (int)hb16.u;
        u32 b0 = (u32)__shfl(hbits,  0, 64);
        u32 b1 = (u32)__shfl(hbits, 16, 64);
        u32 b2 = (u32)__shfl(hbits, 32, 64);
        u32 b3 = (u32)__shfl(hbits, 48, 64);
        if (lane == 0){
            u64 pk = (u64)(b0 & 0xFFFFu)
                   | ((u64)(b1 & 0xFFFFu) << 16)
                   | ((u64)(b2 & 0xFFFFu) << 32)
                   | ((u64)(b3 & 0xFFFFu) << 48);
            __hip_atomic_store(packed + (long long)t*256 + blockIdx.x*8 + wvid, pk,
                               __ATOMIC_RELAXED, __HIP_MEMORY_SCOPE_AGENT);
        }
        xgc[0]=xgn[0]; xgc[1]=xgn[1]; xgc[2]=xgn[2]; xgc[3]=xgn[3];
    }
}

// ---------------- alpha = sigmoid(hs @ W_fc^T + b_fc) ----------------
__global__ __launch_bounds__(256) void alpha_kernel(
    const u64* __restrict__ packed, const float* __restrict__ wfc,
    const float* __restrict__ bfc, float* __restrict__ alpha)
{
    int row  = blockIdx.x*4 + (threadIdx.x>>6);
    int lane = threadIdx.x & 63;
    const u64* p = packed + (long long)row*256 + 4*lane;
    float s = 0.f;
    #pragma unroll
    for (int q=0;q<4;q++){
        union { u64 u; _Float16 h[4]; } cv; cv.u = p[q];
        float4 wvv = *(const float4*)(wfc + 16*lane + 4*q);
        s += (float)cv.h[0]*wvv.x + (float)cv.h[1]*wvv.y
           + (float)cv.h[2]*wvv.z + (float)cv.h[3]*wvv.w;
    }
    #pragma unroll
    for (int off=32; off>=1; off>>=1) s += __shfl_xor(s, off, 64);
    if (lane==0) alpha[row] = sigm(s + bfc[0]);
}

// ---------------- finalize: affine scans + loss ----------------
__global__ __launch_bounds__(256) void finalize_kernel(
    const float* __restrict__ uttr_pred, const float* __restrict__ timing_label,
    const float* __restrict__ alpha, float* __restrict__ out)
{
    const int n = SS-1;  // 16383
    const int tid = threadIdx.x;
    __shared__ float Ms[256], Cs[256], Pre[256];
    __shared__ int Fi[256];
    float* out_y = out + 1;
    float* out_a = out + 1 + n;
    float* out_u = out + 1 + 2*n;

    int i0 = tid*64;
    int i1 = i0+64; if (i1 > n) i1 = n;

    // pass 1: u, a-scan chunk composition, first mask index
    float M = 1.f, C = 0.f;
    int fi = 0x7fffffff;
    for (int i=i0; i<i1; ++i){
        float u = 1.f - uttr_pred[i+1];
        float a = alpha[i+1];
        out_u[i] = u;
        M = u*M;
        C = u*C + (1.f-u)*a;
        if (timing_label[i] > 0.8f && i < fi) fi = i;
    }
    Ms[tid]=M; Cs[tid]=C; Fi[tid]=fi;
    __syncthreads();
    if (tid==0){
        float x=0.f;
        for (int tt=0; tt<256; ++tt){ Pre[tt]=x; x = Ms[tt]*x + Cs[tt]; }
        int best=0x7fffffff;
        for (int tt=0; tt<256; ++tt) best = min(best, Fi[tt]);
        Fi[0]=best;
    }
    __syncthreads();
    // pass 2: emit a_seq, compose y-scan chunks
    float x = Pre[tid];
    float My=1.f, Cy=0.f;
    for (int i=i0;i<i1;++i){
        float u = 1.f - uttr_pred[i+1];
        float a = alpha[i+1];
        x = u*x + (1.f-u)*a;
        out_a[i] = x;
        float Af = 1.f - x;
        float Bf = x*u;
        My = Af*My;
        Cy = Af*Cy + Bf;
    }
    Ms[tid]=My; Cs[tid]=Cy;
    __syncthreads();
    if (tid==0){
        float y=0.f;
        for (int tt=0;tt<256;++tt){ Pre[tt]=y; y = Ms[tt]*y + Cs[tt]; }
    }
    __syncthreads();
    float y = Pre[tid];
    for (int i=i0;i<i1;++i){
        float ag = out_a[i];
        float u  = out_u[i];
        y = ag*u + (1.f-ag)*y;
        out_y[i] = y;
    }
    __syncthreads();
    if (tid==0){
        int best = Fi[0];
        bool exists = (best != 0x7fffffff);
        int idx = exists ? best : 0;
        float u_at = 1.f - uttr_pred[idx+1];
        float y_at = out_y[idx];
        float y_last = out_y[n-1];
        float loss;
        if (exists) loss = (u_at < 0.5f) ? 0.f : (y_at-0.8f)*(y_at-0.8f);
        else        loss = (y_last >= 0.8f) ? (y_last-0.4f)*(y_last-0.4f) : 0.f;
        out[0] = loss;
    }
}

// ---------------- launch ----------------
extern "C" void kernel_launch(void* const* d_in, const int* in_sizes, int n_in,
                              void* d_out, int out_size, void* d_ws, size_t ws_size,
                              hipStream_t stream)
{
    const float* x    = (const float*)d_in[0];
    const float* up   = (const float*)d_in[1];
    const float* tl   = (const float*)d_in[2];
    // d_in[3] = uttr_label (unused by the math)
    const float* wih  = (const float*)d_in[4];
    const float* whh  = (const float*)d_in[5];
    const float* bih  = (const float*)d_in[6];
    const float* bhh  = (const float*)d_in[7];
    const float* wfc  = (const float*)d_in[8];
    const float* bfc  = (const float*)d_in[9];
    float* out = (float*)d_out;

    char* ws = (char*)d_ws;
    ushort_t* xb   = (ushort_t*)(ws);                      // 32 MB  x bf16
    ushort_t* wb   = (ushort_t*)(ws + 33554432);           //  8 MB  W_ih bf16
    _Float16* xg   = (_Float16*)(ws + 41943040);           // 128 MB xg fp16
    u64*      pkd  = (u64*)     (ws + 176160768);          // 32 MB  packed h history
    float*    alp  = (float*)   (ws + 209715200);          // 64 KB  alpha
    float*    bias = (float*)   (ws + 209780736);          // 16 KB  bias

    (void)hipMemsetAsync(pkd, 0xFF, (size_t)SS*HH*2, stream);   // sentinel init
    prep_kernel<<<81936, 256, 0, stream>>>(x, wih, bih, bhh, xb, wb, bias);
    gemm_kernel<<<dim3(G4H/128, SS/128), 256, 0, stream>>>(xb, wb, bias, xg);
    scan_kernel<<<32, 512, 0, stream>>>(whh, xg, pkd);
    alpha_kernel<<<SS/4, 256, 0, stream>>>(pkd, wfc, bfc, alp);
    finalize_kernel<<<1, 256, 0, stream>>>(up, tl, alp, out);
}

// Round 12
// 27264.868 us; speedup vs baseline: 3.3058x; 1.7089x over previous
//
#include <hip/hip_runtime.h>

#define SS 16384
#define DD 1024
#define HH 1024
#define G4H 4096

typedef unsigned long long u64;
typedef unsigned int u32;
typedef unsigned short ushort_t;

typedef __attribute__((ext_vector_type(8))) short bf16x8;
typedef __attribute__((ext_vector_type(4))) float f32x4;
typedef _Float16 h2 __attribute__((ext_vector_type(2)));

__device__ __forceinline__ float sigm(float x){ return 1.0f/(1.0f+__expf(-x)); }
__device__ __forceinline__ float tanh_fast(float x){ return 1.0f - 2.0f/(__expf(2.0f*x)+1.0f); }

__device__ __forceinline__ ushort_t f2bf(float f){
    u32 u = __float_as_uint(f);
    u32 r = (u + 0x7FFFu + ((u>>16)&1u)) >> 16;
    return (ushort_t)r;
}

#if __has_builtin(__builtin_amdgcn_fdot2)
__device__ __forceinline__ float fdot2f(h2 a, h2 b, float c){
    return __builtin_amdgcn_fdot2(a, b, c, false);
}
#else
__device__ __forceinline__ float fdot2f(h2 a, h2 b, float c){
    return c + (float)a.x*(float)b.x + (float)a.y*(float)b.y;
}
#endif

// ---------------- prep: fp32 -> bf16 conversions + bias ----------------
__global__ __launch_bounds__(256) void prep_kernel(
    const float* __restrict__ x, const float* __restrict__ wih,
    const float* __restrict__ bih, const float* __restrict__ bhh,
    ushort_t* __restrict__ xb, ushort_t* __restrict__ wb, float* __restrict__ bias)
{
    long long i = (long long)blockIdx.x*256 + threadIdx.x;
    const long long NX = (long long)SS*DD;      // 16777216
    const long long NW = (long long)G4H*DD;     // 4194304
    if (i < NX) { xb[i] = f2bf(x[i]); }
    else if (i < NX+NW) { long long j=i-NX; wb[j]=f2bf(wih[j]); }
    else { int j=(int)(i-NX-NW); if (j < G4H) bias[j]=bih[j]+bhh[j]; }
}

// ---------------- GEMM: xg = x @ W_ih^T + bias, fp16 out ----------------
#define LDA 40  // padded LDS row stride (bf16 elems)

__global__ __launch_bounds__(256) void gemm_kernel(
    const ushort_t* __restrict__ A, const ushort_t* __restrict__ B,
    const float* __restrict__ bias, _Float16* __restrict__ Cg)
{
    __shared__ ushort_t At[128*LDA];
    __shared__ ushort_t Bt[128*LDA];
    const int tid  = threadIdx.x;
    const int lane = tid & 63;
    const int wv   = tid >> 6;
    const int wm   = wv >> 1, wn = wv & 1;
    const int m0   = blockIdx.y * 128;
    const int n0   = blockIdx.x * 128;
    const int quad = lane >> 4;
    const int l16  = lane & 15;

    f32x4 acc[4][4];
    #pragma unroll
    for (int a=0;a<4;a++)
      #pragma unroll
      for (int b=0;b<4;b++) acc[a][b] = (f32x4){0.f,0.f,0.f,0.f};

    for (int kb = 0; kb < DD; kb += 32) {
        #pragma unroll
        for (int s=0;s<2;s++){
            int ch  = tid*2+s;            // 0..511
            int row = ch >> 2;
            int ko  = (ch & 3) * 8;
            uint4 va = *(const uint4*)(A + (long long)(m0+row)*DD + kb + ko);
            *(uint4*)(At + row*LDA + ko) = va;
            uint4 vb = *(const uint4*)(B + (long long)(n0+row)*DD + kb + ko);
            *(uint4*)(Bt + row*LDA + ko) = vb;
        }
        __syncthreads();
        bf16x8 af[4], bfr[4];
        #pragma unroll
        for (int mi=0;mi<4;mi++){
            int r = wm*64 + mi*16 + l16;
            af[mi] = *(const bf16x8*)(At + r*LDA + quad*8);
        }
        #pragma unroll
        for (int ni=0;ni<4;ni++){
            int r = wn*64 + ni*16 + l16;
            bfr[ni] = *(const bf16x8*)(Bt + r*LDA + quad*8);
        }
        #pragma unroll
        for (int mi=0;mi<4;mi++)
          #pragma unroll
          for (int ni=0;ni<4;ni++)
            acc[mi][ni] = __builtin_amdgcn_mfma_f32_16x16x32_bf16(af[mi], bfr[ni], acc[mi][ni], 0,0,0);
        __syncthreads();
    }
    #pragma unroll
    for (int mi=0;mi<4;mi++){
      #pragma unroll
      for (int ni=0;ni<4;ni++){
        int col = n0 + wn*64 + ni*16 + l16;
        float bv = bias[col];
        #pragma unroll
        for (int r=0;r<4;r++){
            int rowg = m0 + wm*64 + mi*16 + quad*4 + r;
            Cg[(long long)rowg*G4H + col] = (_Float16)(acc[mi][ni][r] + bv);
        }
      }
    }
}

// ---------------- persistent LSTM scan ----------------
// FINAL configuration = round-4/round-9 optimum (27.3-27.5 ms), the sharp
// local optimum on every probed axis:
//  - 64 blocks x 4 waves (1 block/CU, 1 wave/SIMD): r3 256x256=46.5ms,
//    r11 32x512 (identical discipline, no spill)=46.6ms -- 2 waves/SIMD
//    serialize the VALU-dense compute and delay the critical-path store.
//  - wave 0 ONLY polls + stages to double-buffered LDS.
//  - poll = 4 x u64 agent-scope atomic loads at stride 512B (contiguous
//    512B wave bursts; r8's dense chunks + sc0 sc1: +2.6ms).
//  - s_sleep(1) throttle from retry 1 (r5-style tight spin: catastrophic;
//    r6 A/B double-issue: +2.1ms).
//  - r10's 1024-thr geometry: VGPR capped at 64 -> W spilled -> 3.3x.
// Residual ~4000 cy/step = store->agent-visibility RT + detect + barrier +
// compute + max-of-64 jitter of a chip-wide dependent chain x 16384 steps.
__device__ __forceinline__ bool has_sent(u64 v){
    u32 lo = (u32)v, hi = (u32)(v>>32);
    return ((lo & 0xFFFFu)==0xFFFFu) | ((lo>>16)==0xFFFFu) |
           ((hi & 0xFFFFu)==0xFFFFu) | ((hi>>16)==0xFFFFu);
}

__global__ __launch_bounds__(256, 1) void scan_kernel(
    const float* __restrict__ whh, const _Float16* __restrict__ xg,
    u64* __restrict__ packed)
{
    __shared__ u64 hbuf[2][256];
    const int tid  = threadIdx.x;
    const int lane = tid & 63;
    const int wvid = tid >> 6;
    const int rr   = lane >> 4;       // unit-in-wave 0..3
    const int cc   = lane & 15;       // 64-col chunk 0..15
    const int hu   = blockIdx.x*16 + wvid*4 + rr;

    // W_hh slice: gate j row (j*HH + hu), cols 64*cc + [0..63], as packed
    // f16 pairs, chunk-rotated by cc (8 f16 per 16B chunk).
    h2 W[4][32];
    #pragma unroll
    for (int j=0;j<4;j++){
        const float* rp = whh + (long long)(j*HH + hu)*HH + 64*cc;
        #pragma unroll
        for (int m=0;m<8;m++){
            int g = (m + cc) & 7;
            float4 v0 = *(const float4*)(rp + 8*g);
            float4 v1 = *(const float4*)(rp + 8*g + 4);
            h2 a, b, c2, d;
            a.x=(_Float16)v0.x; a.y=(_Float16)v0.y;
            b.x=(_Float16)v0.z; b.y=(_Float16)v0.w;
            c2.x=(_Float16)v1.x; c2.y=(_Float16)v1.y;
            d.x=(_Float16)v1.z; d.y=(_Float16)v1.w;
            W[j][4*m+0]=a; W[j][4*m+1]=b; W[j][4*m+2]=c2; W[j][4*m+3]=d;
        }
    }

    float c_st = 0.0f;
    float xgc[4];
    #pragma unroll
    for (int j=0;j<4;j++) xgc[j] = (float)xg[(long long)j*HH + hu];

    for (int t=0; t<SS; ++t){
        const int par = t & 1;
        // prefetch next step's xg (overlaps the poll)
        float xgn[4] = {0.f,0.f,0.f,0.f};
        if (t+1 < SS){
            #pragma unroll
            for (int j=0;j<4;j++)
                xgn[j] = (float)xg[(long long)(t+1)*G4H + j*HH + hu];
        }

        if (wvid == 0){
            if (t == 0){
                hbuf[0][lane]=0; hbuf[0][lane+64]=0;
                hbuf[0][lane+128]=0; hbuf[0][lane+192]=0;
            } else {
                const u64* src = packed + (long long)(t-1)*256 + lane;
                u64 v0=0,v1=0,v2=0,v3=0;
                int spin = 0;
                for (;;){
                    v0 = __hip_atomic_load(src      , __ATOMIC_RELAXED, __HIP_MEMORY_SCOPE_AGENT);
                    v1 = __hip_atomic_load(src +  64, __ATOMIC_RELAXED, __HIP_MEMORY_SCOPE_AGENT);
                    v2 = __hip_atomic_load(src + 128, __ATOMIC_RELAXED, __HIP_MEMORY_SCOPE_AGENT);
                    v3 = __hip_atomic_load(src + 192, __ATOMIC_RELAXED, __HIP_MEMORY_SCOPE_AGENT);
                    if (!(has_sent(v0)|has_sent(v1)|has_sent(v2)|has_sent(v3))) break;
                    if (++spin > (1<<19)) break;   // deadlock insurance
                    if (spin > 1024) __builtin_amdgcn_s_sleep(8);
                    else             __builtin_amdgcn_s_sleep(1);
                }
                hbuf[par][lane]     = v0;
                hbuf[par][lane+64]  = v1;
                hbuf[par][lane+128] = v2;
                hbuf[par][lane+192] = v3;
            }
        }
        __syncthreads();

        // read this lane's 128B h slice, chunk-rotated (matches W rotation)
        union { uint4 v4[8]; h2 hh[32]; } H;
        {
            const char* hb = (const char*)(hbuf[par] + 16*cc);
            #pragma unroll
            for (int m=0;m<8;m++){
                H.v4[m] = *(const uint4*)(hb + 16*((m+cc)&7));
            }
        }

        float s0=0.f, s1=0.f, s2=0.f, s3=0.f;
        #pragma unroll
        for (int m=0;m<32;m++){
            s0 = fdot2f(W[0][m], H.hh[m], s0);
            s1 = fdot2f(W[1][m], H.hh[m], s1);
            s2 = fdot2f(W[2][m], H.hh[m], s2);
            s3 = fdot2f(W[3][m], H.hh[m], s3);
        }
        // reduce over the 16 cc-lanes of this rr-group
        #pragma unroll
        for (int off=8; off>=1; off>>=1){
            s0 += __shfl_xor(s0, off, 64);
            s1 += __shfl_xor(s1, off, 64);
            s2 += __shfl_xor(s2, off, 64);
            s3 += __shfl_xor(s3, off, 64);
        }
        // every lane in group rr now holds unit hu's complete gate sums
        float zi = s0 + xgc[0];
        float zf = s1 + xgc[1];
        float zg = s2 + xgc[2];
        float zo = s3 + xgc[3];
        c_st = sigm(zf)*c_st + sigm(zi)*tanh_fast(zg);
        float hval = sigm(zo)*tanh_fast(c_st);

        union { _Float16 h; ushort_t u; } hb16; hb16.h = (_Float16)hval;
        int hbits = (int)hb16.u;
        u32 b0 = (u32)__shfl(hbits,  0, 64);
        u32 b1 = (u32)__shfl(hbits, 16, 64);
        u32 b2 = (u32)__shfl(hbits, 32, 64);
        u32 b3 = (u32)__shfl(hbits, 48, 64);
        if (lane == 0){
            u64 pk = (u64)(b0 & 0xFFFFu)
                   | ((u64)(b1 & 0xFFFFu) << 16)
                   | ((u64)(b2 & 0xFFFFu) << 32)
                   | ((u64)(b3 & 0xFFFFu) << 48);
            __hip_atomic_store(packed + (long long)t*256 + blockIdx.x*4 + wvid, pk,
                               __ATOMIC_RELAXED, __HIP_MEMORY_SCOPE_AGENT);
        }
        xgc[0]=xgn[0]; xgc[1]=xgn[1]; xgc[2]=xgn[2]; xgc[3]=xgn[3];
    }
}

// ---------------- alpha = sigmoid(hs @ W_fc^T + b_fc) ----------------
__global__ __launch_bounds__(256) void alpha_kernel(
    const u64* __restrict__ packed, const float* __restrict__ wfc,
    const float* __restrict__ bfc, float* __restrict__ alpha)
{
    int row  = blockIdx.x*4 + (threadIdx.x>>6);
    int lane = threadIdx.x & 63;
    const u64* p = packed + (long long)row*256 + 4*lane;
    float s = 0.f;
    #pragma unroll
    for (int q=0;q<4;q++){
        union { u64 u; _Float16 h[4]; } cv; cv.u = p[q];
        float4 wvv = *(const float4*)(wfc + 16*lane + 4*q);
        s += (float)cv.h[0]*wvv.x + (float)cv.h[1]*wvv.y
           + (float)cv.h[2]*wvv.z + (float)cv.h[3]*wvv.w;
    }
    #pragma unroll
    for (int off=32; off>=1; off>>=1) s += __shfl_xor(s, off, 64);
    if (lane==0) alpha[row] = sigm(s + bfc[0]);
}

// ---------------- finalize: affine scans + loss ----------------
__global__ __launch_bounds__(256) void finalize_kernel(
    const float* __restrict__ uttr_pred, const float* __restrict__ timing_label,
    const float* __restrict__ alpha, float* __restrict__ out)
{
    const int n = SS-1;  // 16383
    const int tid = threadIdx.x;
    __shared__ float Ms[256], Cs[256], Pre[256];
    __shared__ int Fi[256];
    float* out_y = out + 1;
    float* out_a = out + 1 + n;
    float* out_u = out + 1 + 2*n;

    int i0 = tid*64;
    int i1 = i0+64; if (i1 > n) i1 = n;

    // pass 1: u, a-scan chunk composition, first mask index
    float M = 1.f, C = 0.f;
    int fi = 0x7fffffff;
    for (int i=i0; i<i1; ++i){
        float u = 1.f - uttr_pred[i+1];
        float a = alpha[i+1];
        out_u[i] = u;
        M = u*M;
        C = u*C + (1.f-u)*a;
        if (timing_label[i] > 0.8f && i < fi) fi = i;
    }
    Ms[tid]=M; Cs[tid]=C; Fi[tid]=fi;
    __syncthreads();
    if (tid==0){
        float x=0.f;
        for (int tt=0; tt<256; ++tt){ Pre[tt]=x; x = Ms[tt]*x + Cs[tt]; }
        int best=0x7fffffff;
        for (int tt=0; tt<256; ++tt) best = min(best, Fi[tt]);
        Fi[0]=best;
    }
    __syncthreads();
    // pass 2: emit a_seq, compose y-scan chunks
    float x = Pre[tid];
    float My=1.f, Cy=0.f;
    for (int i=i0;i<i1;++i){
        float u = 1.f - uttr_pred[i+1];
        float a = alpha[i+1];
        x = u*x + (1.f-u)*a;
        out_a[i] = x;
        float Af = 1.f - x;
        float Bf = x*u;
        My = Af*My;
        Cy = Af*Cy + Bf;
    }
    Ms[tid]=My; Cs[tid]=Cy;
    __syncthreads();
    if (tid==0){
        float y=0.f;
        for (int tt=0;tt<256;++tt){ Pre[tt]=y; y = Ms[tt]*y + Cs[tt]; }
    }
    __syncthreads();
    float y = Pre[tid];
    for (int i=i0;i<i1;++i){
        float ag = out_a[i];
        float u  = out_u[i];
        y = ag*u + (1.f-ag)*y;
        out_y[i] = y;
    }
    __syncthreads();
    if (tid==0){
        int best = Fi[0];
        bool exists = (best != 0x7fffffff);
        int idx = exists ? best : 0;
        float u_at = 1.f - uttr_pred[idx+1];
        float y_at = out_y[idx];
        float y_last = out_y[n-1];
        float loss;
        if (exists) loss = (u_at < 0.5f) ? 0.f : (y_at-0.8f)*(y_at-0.8f);
        else        loss = (y_last >= 0.8f) ? (y_last-0.4f)*(y_last-0.4f) : 0.f;
        out[0] = loss;
    }
}

// ---------------- launch ----------------
extern "C" void kernel_launch(void* const* d_in, const int* in_sizes, int n_in,
                              void* d_out, int out_size, void* d_ws, size_t ws_size,
                              hipStream_t stream)
{
    const float* x    = (const float*)d_in[0];
    const float* up   = (const float*)d_in[1];
    const float* tl   = (const float*)d_in[2];
    // d_in[3] = uttr_label (unused by the math)
    const float* wih  = (const float*)d_in[4];
    const float* whh  = (const float*)d_in[5];
    const float* bih  = (const float*)d_in[6];
    const float* bhh  = (const float*)d_in[7];
    const float* wfc  = (const float*)d_in[8];
    const float* bfc  = (const float*)d_in[9];
    float* out = (float*)d_out;

    char* ws = (char*)d_ws;
    ushort_t* xb   = (ushort_t*)(ws);                      // 32 MB  x bf16
    ushort_t* wb   = (ushort_t*)(ws + 33554432);           //  8 MB  W_ih bf16
    _Float16* xg   = (_Float16*)(ws + 41943040);           // 128 MB xg fp16
    u64*      pkd  = (u64*)     (ws + 176160768);          // 32 MB  packed h history
    float*    alp  = (float*)   (ws + 209715200);          // 64 KB  alpha
    float*    bias = (float*)   (ws + 209780736);          // 16 KB  bias

    (void)hipMemsetAsync(pkd, 0xFF, (size_t)SS*HH*2, stream);   // sentinel init
    prep_kernel<<<81936, 256, 0, stream>>>(x, wih, bih, bhh, xb, wb, bias);
    gemm_kernel<<<dim3(G4H/128, SS/128), 256, 0, stream>>>(xb, wb, bias, xg);
    scan_kernel<<<64, 256, 0, stream>>>(whh, xg, pkd);
    alpha_kernel<<<SS/4, 256, 0, stream>>>(pkd, wfc, bfc, alp);
    finalize_kernel<<<1, 256, 0, stream>>>(up, tl, alp, out);
}